// Round 1
// 324.370 us; speedup vs baseline: 1.0116x; 1.0116x over previous
//
#include <hip/hip_runtime.h>
#include <hip/hip_bf16.h>

// ---------------------------------------------------------------------------
// SolitonInteractionLayer: fused PDE (sine-Gordon + KdV + Heimburg-Jackson,
// RK4, 3 steps) along T, then out = evolved @ W^T + b via bf16 MFMA GEMM.
//
// PDE: causal stencils only (shift pads zeros on the left). Max dependence
// depth = 12 rhs evals * 4 (dxxxx) = 48 -> tile T with left halo 48, no
// cross-block communication. Thread owns 16 contiguous t-points in regs;
// chunk-boundary halo (4 vals) moves via __shfl_up within 32-lane groups
// (32 chunks per d-column -> 512-t tile, 464 interior, 1.125x redundancy).
// Substep loops iterate i DESCENDING: causal stencils read only lower i,
// overwritten later -> safe in-place update.
//
// R5: step-loops #pragma unroll 1 (code ~24 KB, fits I$) but launch_bounds
// back to (256,2): R4's (256,4) capped VGPR at 64 < ~130 live floats ->
// scratch spill (3.2 GB HBM traffic, 930 us). 2 waves/SIMD x ILP=16 points
// is enough issue parallelism; spill avoidance dominates occupancy here.
//
// R6 (this round): GEMM rewritten 128x256/single-buffer -> 256x256/BK64,
// 8 waves, double-buffered LDS (128 KiB), 2-phase pipeline (stage next
// tile BEFORE computing current, ONE __syncthreads per K-step). Residual
// time after pde (~105 us for 34.4 GFLOP ~= 330 TF) says the old 2-barrier
// loop left staging latency exposed at K=1024 (16 iters). 2-phase 256^2
// reference: 655-682 TF -> predict gemm ~55 us, total ~275 us.
// ---------------------------------------------------------------------------

typedef __bf16 bf16x8 __attribute__((ext_vector_type(8)));
typedef __bf16 bf16x4 __attribute__((ext_vector_type(4)));
typedef float  floatx4 __attribute__((ext_vector_type(4)));

#define T_DIM 4096
#define D_DIM 1024
#define NP    16      // t-points per thread chunk
#define HALO  48      // 3 chunks
#define NCH   32      // chunks per d-column (one 32-lane shfl group)
#define TINT  (NCH * NP - HALO)   // 464 interior t per block
#define NTT   9       // ceil(4096/464)

__device__ __forceinline__ float sg_rhs(float c, float m1, float m2, float vv) {
  float dxx = fmaf(-2.f, m1, c) + m2;           // u - 2u1 + u2   (C2 = 1)
  return dxx - __sinf(c) - 0.5f * vv;
}
__device__ __forceinline__ float kdv_rhs(float c, float m1, float m2, float m3) {
  float dxu = c - m1;
  float dx3 = fmaf(-3.f, m1, c) + fmaf(3.f, m2, -m3);   // u -3u1 +3u2 -u3
  return fmaf(-6.f * c, dxu, -dx3 - 0.5f * c);
}
__device__ __forceinline__ float hj_rhs(float c, float m1, float m2, float m3,
                                        float m4, float vv) {
  float gi = (fmaf(c, c, c) + 1.f) * (c - m1);          // (1+u+u^2)*dx(u) @ i
  float gm = (fmaf(m1, m1, m1) + 1.f) * (m1 - m2);      //               @ i-1
  float d4 = fmaf(-4.f, m3, fmaf(6.f, m2, fmaf(-4.f, m1, c))) + m4;  // dxxxx
  return (gi - gm) - d4 - 0.5f * vv;
}

// stencil access with register halo (compile-time idx after unroll)
#define AT(F, i) (((i) >= 0) ? F[(i)] : hl[4 + (i)])
// pull neighbor chunk's top-4 values (lane tr-1 within 32-lane group).
// tr==0 receives its own values: contamination propagates <=4 idx per rhs
// eval -> stays strictly left of t0 after all 12 evals (HALO = 48 = 12*4).
#define XCHG(F) do { \
    hl[0] = __shfl_up(F[NP - 4], 1, 32); \
    hl[1] = __shfl_up(F[NP - 3], 1, 32); \
    hl[2] = __shfl_up(F[NP - 2], 1, 32); \
    hl[3] = __shfl_up(F[NP - 1], 1, 32); \
  } while (0)

__global__ __launch_bounds__(256, 2)
void pde_kernel(const float* __restrict__ x, const float* __restrict__ mix,
                __bf16* __restrict__ evout) {
  const int tid  = threadIdx.x;
  const int tr   = tid & 31;       // chunk index within d-column (shfl group)
  const int dcol = tid >> 5;       // 0..7
  // XCD-pairing swizzle: y = q*8 + r (q=0..15, r=0..7) -> d-group r*16+q.
  // Blocks (q,r) and (q+1,r) cover adjacent 8-wide d halves of the same
  // 64B line and sit 72 apart in linear dispatch id (72 % 8 == 0 -> same
  // XCD under round-robin) so L2 serves the second half-line.
  const int yq   = blockIdx.y >> 3;
  const int yr   = blockIdx.y & 7;
  const int d    = (yr * 16 + yq) * 8 + dcol;
  const int b    = blockIdx.z;
  const int t0   = blockIdx.x * TINT;
  const int tb   = t0 - HALO + tr * NP;   // t of reg[0]

  // softmax(solver_mix) per-thread (3 elements)
  float s0 = mix[0], s1 = mix[1], s2 = mix[2];
  float mxv = fmaxf(s0, fmaxf(s1, s2));
  float e0 = __expf(s0 - mxv), e1 = __expf(s1 - mxv), e2 = __expf(s2 - mxv);
  float inv = 1.f / (e0 + e1 + e2);
  float w0 = e0 * inv, w1 = e1 * inv, w2 = e2 * inv;

  const float* xp = x + ((size_t)b * T_DIM) * D_DIM + d;

  float u0[NP], u[NP], v[NP], ut[NP], vt[NP], au[NP], av[NP], ev[NP], hl[4];

  #pragma unroll
  for (int j = 0; j < NP; ++j) {
    int t = tb + j;
    float xv = (t >= 0 && t < T_DIM) ? xp[(size_t)t * D_DIM] : 0.f;
    // fast tanh: 2*tanh(x) = 2 - 4/(e^{2x}+1); clamp avoids inf/inf
    float xc = fminf(fmaxf(xv, -9.f), 9.f);
    float ex = __expf(2.f * xc);
    u0[j] = 2.f - 4.f * __builtin_amdgcn_rcpf(ex + 1.f);
  }

  // ---------------- sine-Gordon (2nd order, dt = 0.05) ----------------
  {
    const float dt = 0.05f, h = 0.025f, w6 = dt * (1.f / 6.f);
    #pragma unroll
    for (int j = 0; j < NP; ++j) { u[j] = u0[j]; v[j] = 0.f; }
    #pragma unroll 1
    for (int s = 0; s < 3; ++s) {
      XCHG(u);
      #pragma unroll
      for (int i = NP - 1; i >= 0; --i) {            // k1
        float k = sg_rhs(u[i], AT(u, i - 1), AT(u, i - 2), v[i]);
        au[i] = v[i]; av[i] = k;
        ut[i] = fmaf(h, v[i], u[i]);
        vt[i] = fmaf(h, k, v[i]);
      }
      XCHG(ut);
      #pragma unroll
      for (int i = NP - 1; i >= 0; --i) {            // k2
        float k = sg_rhs(ut[i], AT(ut, i - 1), AT(ut, i - 2), vt[i]);
        au[i] = fmaf(2.f, vt[i], au[i]); av[i] = fmaf(2.f, k, av[i]);
        float nu = fmaf(h, vt[i], u[i]);             // u + h*k2u (k2u = old vt)
        vt[i] = fmaf(h, k, v[i]);
        ut[i] = nu;
      }
      XCHG(ut);
      #pragma unroll
      for (int i = NP - 1; i >= 0; --i) {            // k3
        float k = sg_rhs(ut[i], AT(ut, i - 1), AT(ut, i - 2), vt[i]);
        au[i] = fmaf(2.f, vt[i], au[i]); av[i] = fmaf(2.f, k, av[i]);
        float nu = fmaf(dt, vt[i], u[i]);
        vt[i] = fmaf(dt, k, v[i]);
        ut[i] = nu;
      }
      XCHG(ut);
      #pragma unroll
      for (int i = NP - 1; i >= 0; --i) {            // k4 + combine
        float k = sg_rhs(ut[i], AT(ut, i - 1), AT(ut, i - 2), vt[i]);
        au[i] += vt[i]; av[i] += k;
        u[i] = fmaf(w6, au[i], u[i]);
        v[i] = fmaf(w6, av[i], v[i]);
      }
    }
    #pragma unroll
    for (int j = 0; j < NP; ++j) ev[j] = w0 * u[j];
  }

  // ---------------- KdV (1st order, dt = 0.025) ----------------
  {
    const float dt = 0.025f, h = 0.0125f, w6 = dt * (1.f / 6.f);
    #pragma unroll
    for (int j = 0; j < NP; ++j) u[j] = u0[j];
    #pragma unroll 1
    for (int s = 0; s < 3; ++s) {
      XCHG(u);
      #pragma unroll
      for (int i = NP - 1; i >= 0; --i) {            // k1
        float k = kdv_rhs(u[i], AT(u, i - 1), AT(u, i - 2), AT(u, i - 3));
        au[i] = k;
        ut[i] = fmaf(h, k, u[i]);
      }
      XCHG(ut);
      #pragma unroll
      for (int i = NP - 1; i >= 0; --i) {            // k2
        float k = kdv_rhs(ut[i], AT(ut, i - 1), AT(ut, i - 2), AT(ut, i - 3));
        au[i] = fmaf(2.f, k, au[i]);
        ut[i] = fmaf(h, k, u[i]);
      }
      XCHG(ut);
      #pragma unroll
      for (int i = NP - 1; i >= 0; --i) {            // k3
        float k = kdv_rhs(ut[i], AT(ut, i - 1), AT(ut, i - 2), AT(ut, i - 3));
        au[i] = fmaf(2.f, k, au[i]);
        ut[i] = fmaf(dt, k, u[i]);
      }
      XCHG(ut);
      #pragma unroll
      for (int i = NP - 1; i >= 0; --i) {            // k4 + combine
        float k = kdv_rhs(ut[i], AT(ut, i - 1), AT(ut, i - 2), AT(ut, i - 3));
        u[i] = fmaf(w6, au[i] + k, u[i]);
      }
    }
    #pragma unroll
    for (int j = 0; j < NP; ++j) ev[j] = fmaf(w1, u[j], ev[j]);
  }

  // ---------------- Heimburg-Jackson (2nd order, dt = 0.025) ----------------
  {
    const float dt = 0.025f, h = 0.0125f, w6 = dt * (1.f / 6.f);
    #pragma unroll
    for (int j = 0; j < NP; ++j) { u[j] = u0[j]; v[j] = 0.f; }
    #pragma unroll 1
    for (int s = 0; s < 3; ++s) {
      XCHG(u);
      #pragma unroll
      for (int i = NP - 1; i >= 0; --i) {            // k1
        float k = hj_rhs(u[i], AT(u, i - 1), AT(u, i - 2), AT(u, i - 3),
                         AT(u, i - 4), v[i]);
        au[i] = v[i]; av[i] = k;
        ut[i] = fmaf(h, v[i], u[i]);
        vt[i] = fmaf(h, k, v[i]);
      }
      XCHG(ut);
      #pragma unroll
      for (int i = NP - 1; i >= 0; --i) {            // k2
        float k = hj_rhs(ut[i], AT(ut, i - 1), AT(ut, i - 2), AT(ut, i - 3),
                         AT(ut, i - 4), vt[i]);
        au[i] = fmaf(2.f, vt[i], au[i]); av[i] = fmaf(2.f, k, av[i]);
        float nu = fmaf(h, vt[i], u[i]);
        vt[i] = fmaf(h, k, v[i]);
        ut[i] = nu;
      }
      XCHG(ut);
      #pragma unroll
      for (int i = NP - 1; i >= 0; --i) {            // k3
        float k = hj_rhs(ut[i], AT(ut, i - 1), AT(ut, i - 2), AT(ut, i - 3),
                         AT(ut, i - 4), vt[i]);
        au[i] = fmaf(2.f, vt[i], au[i]); av[i] = fmaf(2.f, k, av[i]);
        float nu = fmaf(dt, vt[i], u[i]);
        vt[i] = fmaf(dt, k, v[i]);
        ut[i] = nu;
      }
      XCHG(ut);
      #pragma unroll
      for (int i = NP - 1; i >= 0; --i) {            // k4 + combine
        float k = hj_rhs(ut[i], AT(ut, i - 1), AT(ut, i - 2), AT(ut, i - 3),
                         AT(ut, i - 4), vt[i]);
        au[i] += vt[i]; av[i] += k;
        u[i] = fmaf(w6, au[i], u[i]);
        v[i] = fmaf(w6, av[i], v[i]);
      }
    }
    #pragma unroll
    for (int j = 0; j < NP; ++j) ev[j] = fmaf(w2, u[j], ev[j]);
  }

  // store interior chunks (tr >= 3) as bf16 A-matrix [b*T+t][d]
  if (tr >= 3) {
    #pragma unroll
    for (int j = 0; j < NP; ++j) {
      int t = tb + j;
      if (t < T_DIM)
        evout[((size_t)(b * T_DIM + t)) * D_DIM + d] = (__bf16)ev[j];
    }
  }
}

// ---------------------------------------------------------------------------
// W (fp32, [E][D]) -> bf16
// ---------------------------------------------------------------------------
__global__ __launch_bounds__(256)
void convert_w(const float* __restrict__ W, __bf16* __restrict__ Wb) {
  int i = blockIdx.x * 256 + threadIdx.x;   // over D*D/4
  float4 f = ((const float4*)W)[i];
  bf16x4 o = {(__bf16)f.x, (__bf16)f.y, (__bf16)f.z, (__bf16)f.w};
  ((bf16x4*)Wb)[i] = o;
}

// ---------------------------------------------------------------------------
// GEMM: out[m][n] = sum_k A[m][k] * Wb[n][k] + bias[n]
// M=16384, N=1024, K=1024.
//
// R6: 256x256 block tile, BK=64, 512 threads / 8 waves (2Mx4N, each wave a
// 128x64 output tile, acc[8][4]), mfma_f32_16x16x32_bf16. Double-buffered
// LDS (2 x (A 32KB + B 32KB) = 128 KiB -> 1 block/CU) with the catalog's
// minimum 2-phase schedule: STAGE(next) issued BEFORE ds_read+MFMA(cur),
// single __syncthreads per K-step (its vmcnt(0) drain lands after the MFMA
// phase, so prefetch latency hides under compute). Staging via
// global_load_lds width=16, linear LDS dest; bank conflicts killed by XOR
// swizzle: 16B granule kc of row r lives at slot kc^(r&7), inverse-swizzled
// on the global source address (both-sides-or-neither rule).
// Grid (64,4): same-A blocks are 64 apart in dispatch id (64%8==0 -> same
// XCD) for A-panel L2 reuse; Wb (2MB) fits each XCD's 4MB L2.
// ---------------------------------------------------------------------------
#define GK   1024

__global__ __launch_bounds__(512, 1)
void gemm_kernel(const __bf16* __restrict__ A, const __bf16* __restrict__ Bw,
                 const float* __restrict__ bias, float* __restrict__ out) {
  __shared__ __align__(16) __bf16 As[2][256 * 64];   // 2 x 32 KB
  __shared__ __align__(16) __bf16 Bs[2][256 * 64];   // 2 x 32 KB

  const int tid  = threadIdx.x;
  const int lane = tid & 63;
  const int wid  = tid >> 6;           // 0..7
  const int m0   = blockIdx.x * 256;
  const int n0   = blockIdx.y * 256;
  const int wm   = (wid >> 2) * 128;   // 0 or 128
  const int wn   = (wid & 3) * 64;     // 0..192
  const int l15  = lane & 15;
  const int quad = lane >> 4;

  // staging: each global_load_lds covers 8 rows x 64 cols; lane i -> row
  // (i>>3) of the 8-row block, swizzled granule kc = (i&7) ^ row; LDS dest
  // is wave-uniform base + lane*16 (HW rule).
  const int sr  = lane >> 3;                 // 0..7 row within 8-row block
  const int skc = (lane & 7) ^ sr;           // inverse-swizzled global granule

  // wave w stages rows [w*32, w*32+32) of both tiles (4 instrs each)
  const __bf16* aBase = A  + (size_t)(m0 + wid * 32 + sr) * GK + skc * 8;
  const __bf16* bBase = Bw + (size_t)(n0 + wid * 32 + sr) * GK + skc * 8;

#define STAGE(buf, kt) do {                                                   \
    _Pragma("unroll")                                                         \
    for (int p = 0; p < 4; ++p)                                               \
      __builtin_amdgcn_global_load_lds(                                       \
          (const uint32_t*)(aBase + (size_t)(p * 8) * GK + (kt)),             \
          (uint32_t*)&As[buf][(wid * 32 + p * 8) * 64], 16, 0, 0);            \
    _Pragma("unroll")                                                         \
    for (int p = 0; p < 4; ++p)                                               \
      __builtin_amdgcn_global_load_lds(                                       \
          (const uint32_t*)(bBase + (size_t)(p * 8) * GK + (kt)),             \
          (uint32_t*)&Bs[buf][(wid * 32 + p * 8) * 64], 16, 0, 0);            \
  } while (0)

  floatx4 acc[8][4] = {};

  STAGE(0, 0);
  __syncthreads();                 // vmcnt(0): buffer 0 ready

  int cur = 0;
  for (int kt = 64; kt <= GK; kt += 64) {
    if (kt < GK) STAGE(cur ^ 1, kt);        // prefetch next tile first
    const __bf16* as = As[cur];
    const __bf16* bs = Bs[cur];
    #pragma unroll
    for (int c = 0; c < 2; ++c) {           // two K=32 chunks
      bf16x8 af[8], bfr[4];
      int kcg = c * 4 + quad;               // global 16B granule within row
      #pragma unroll
      for (int i = 0; i < 8; ++i) {
        int ra = wm + i * 16 + l15;
        af[i] = *(const bf16x8*)(&as[ra * 64 + ((kcg ^ (ra & 7)) * 8)]);
      }
      #pragma unroll
      for (int j = 0; j < 4; ++j) {
        int rb = wn + j * 16 + l15;
        bfr[j] = *(const bf16x8*)(&bs[rb * 64 + ((kcg ^ (rb & 7)) * 8)]);
      }
      #pragma unroll
      for (int i = 0; i < 8; ++i)
        #pragma unroll
        for (int j = 0; j < 4; ++j)
          acc[i][j] = __builtin_amdgcn_mfma_f32_16x16x32_bf16(
              af[i], bfr[j], acc[i][j], 0, 0, 0);
    }
    __syncthreads();               // drains vmcnt: next buffer ready; also
    cur ^= 1;                      // guards re-stage of this buffer
  }
#undef STAGE

  // epilogue: D[m=quad*4+r][n=l15] per 16x16 tile; add bias
  #pragma unroll
  for (int j = 0; j < 4; ++j) {
    int n = n0 + wn + j * 16 + l15;
    float bv = bias[n];
    #pragma unroll
    for (int i = 0; i < 8; ++i) {
      int mb = m0 + wm + i * 16 + quad * 4;
      #pragma unroll
      for (int r = 0; r < 4; ++r)
        out[(size_t)(mb + r) * 1024 + n] = acc[i][j][r] + bv;
    }
  }
}

// ---------------------------------------------------------------------------
extern "C" void kernel_launch(void* const* d_in, const int* in_sizes, int n_in,
                              void* d_out, int out_size, void* d_ws, size_t ws_size,
                              hipStream_t stream) {
  const float* x    = (const float*)d_in[0];
  const float* mix  = (const float*)d_in[1];
  const float* W    = (const float*)d_in[2];
  const float* bias = (const float*)d_in[3];
  float* out = (float*)d_out;

  __bf16* ev = (__bf16*)d_ws;                                     // 32 MiB
  __bf16* Wb = (__bf16*)((char*)d_ws + (size_t)32 * 1024 * 1024); // 2 MiB

  convert_w<<<dim3((D_DIM * D_DIM / 4) / 256), 256, 0, stream>>>(W, Wb);
  pde_kernel<<<dim3(NTT, 128, 4), 256, 0, stream>>>(x, mix, ev);
  gemm_kernel<<<dim3(16384 / 256, 1024 / 256), 512, 0, stream>>>(ev, Wb, bias, out);
}

// Round 2
// 323.182 us; speedup vs baseline: 1.0154x; 1.0037x over previous
//
#include <hip/hip_runtime.h>
#include <hip/hip_bf16.h>

// ---------------------------------------------------------------------------
// SolitonInteractionLayer: fused PDE (sine-Gordon + KdV + Heimburg-Jackson,
// RK4, 3 steps) along T, then out = evolved @ W^T + b via bf16 MFMA GEMM.
//
// PDE: causal stencils only (shift pads zeros on the left). Max dependence
// depth = 12 rhs evals * 4 (dxxxx) = 48 -> tile T with left halo 48, no
// cross-block communication. Thread owns NP contiguous t-points in regs;
// chunk-boundary halo (4 vals) moves via __shfl_up within the shfl group.
// Substep loops iterate i DESCENDING: causal stencils read only lower i,
// overwritten later -> safe in-place update. Contamination from the group-
// leader's self-received halo advances <=4 idx per rhs eval; 12 evals * 4 =
// 48 = HALO -> interior (tr >= HALO/NP) is exact.
//
// R7 (this round):
//  - NP 16->8, NCH 32->64 (wave = one d-column, one 64-wide shfl group).
//    Same tile (512), same halo, bitwise-identical math; per-thread register
//    state halves (~116 -> ~70 floats) -> VGPR ~96-112 -> 4-5 waves/SIMD
//    (was 2). Attacks the 30% VALU-idle (latency) seen at Occupancy 21%.
//  - HJ algebraic reuse: gm(i) == gi(i-1); precompute g[] once per substep
//    (boundary g[-1] from halo regs), rhs uses g[i]-g[i-1]. Saves ~4 ops/
//    point/eval x 12 evals (~8% of pde VALU). Bitwise-identical values.
//  - launch_bounds (256,4): cap 128 VGPR >= ~96 needed; forces allocator
//    to stay lean (min=2 would let it balloon regs for scheduling).
//  - GEMM: __syncthreads() drained the prefetch (vmcnt(0)) -> R6's double
//    buffer never pipelined. Now T4 counted waits: s_waitcnt vmcnt(8) + raw
//    s_barrier keeps the 8 prefetch loads in flight across the barrier;
//    peeled last iteration drains vmcnt(0). lgkmcnt(0)+sched_barrier before
//    the read-done barrier (rule: compiler may move reg-only MFMA past asm).
// ---------------------------------------------------------------------------

typedef __bf16 bf16x8 __attribute__((ext_vector_type(8)));
typedef __bf16 bf16x4 __attribute__((ext_vector_type(4)));
typedef float  floatx4 __attribute__((ext_vector_type(4)));

#define T_DIM 4096
#define D_DIM 1024
#define NP    8       // t-points per thread chunk
#define HALO  48      // 6 chunks
#define NCH   64      // chunks per d-column (one 64-lane shfl group = 1 wave)
#define TINT  (NCH * NP - HALO)   // 464 interior t per block
#define NTT   9       // ceil(4096/464)

__device__ __forceinline__ float sg_rhs(float c, float m1, float m2, float vv) {
  float dxx = fmaf(-2.f, m1, c) + m2;           // u - 2u1 + u2   (C2 = 1)
  return dxx - __sinf(c) - 0.5f * vv;
}
__device__ __forceinline__ float kdv_rhs(float c, float m1, float m2, float m3) {
  float dxu = c - m1;
  float dx3 = fmaf(-3.f, m1, c) + fmaf(3.f, m2, -m3);   // u -3u1 +3u2 -u3
  return fmaf(-6.f * c, dxu, -dx3 - 0.5f * c);
}
// HJ with g-reuse: k = (g[i] - g[i-1]) - dxxxx - 0.5 v
__device__ __forceinline__ float hj_rhs2(float c, float m1, float m2, float m3,
                                         float m4, float dg, float vv) {
  float d4 = fmaf(-4.f, m3, fmaf(6.f, m2, fmaf(-4.f, m1, c))) + m4;  // dxxxx
  return (dg - d4) - 0.5f * vv;
}
__device__ __forceinline__ float hj_g(float c, float m1) {
  return (fmaf(c, c, c) + 1.f) * (c - m1);      // (1+u+u^2)*dx(u)
}

// stencil access with register halo (compile-time idx after unroll)
#define AT(F, i) (((i) >= 0) ? F[(i)] : hl[4 + (i)])
// pull neighbor chunk's top-4 values (lane tr-1 within the 64-lane group).
// tr==0 receives its own values: only points i<=3 of chunk 0 are wrong ->
// garbage zone [t0-48, t0-44), advancing <=4/eval -> reaches exactly t0
// after 12 evals; interior (tr >= 6) exact.
#define XCHG(F) do { \
    hl[0] = __shfl_up(F[NP - 4], 1, 64); \
    hl[1] = __shfl_up(F[NP - 3], 1, 64); \
    hl[2] = __shfl_up(F[NP - 2], 1, 64); \
    hl[3] = __shfl_up(F[NP - 1], 1, 64); \
  } while (0)

__global__ __launch_bounds__(256, 4)
void pde_kernel(const float* __restrict__ x, const float* __restrict__ mix,
                __bf16* __restrict__ evout) {
  const int tid  = threadIdx.x;
  const int tr   = tid & 63;       // chunk index within d-column (= lane)
  const int dcol = tid >> 6;       // 0..3 (wave id)
  const int d    = blockIdx.y * 4 + dcol;
  const int b    = blockIdx.z;
  const int t0   = blockIdx.x * TINT;
  const int tb   = t0 - HALO + tr * NP;   // t of reg[0]

  // softmax(solver_mix) per-thread (3 elements)
  float s0 = mix[0], s1 = mix[1], s2 = mix[2];
  float mxv = fmaxf(s0, fmaxf(s1, s2));
  float e0 = __expf(s0 - mxv), e1 = __expf(s1 - mxv), e2 = __expf(s2 - mxv);
  float inv = 1.f / (e0 + e1 + e2);
  float w0 = e0 * inv, w1 = e1 * inv, w2 = e2 * inv;

  const float* xp = x + ((size_t)b * T_DIM) * D_DIM + d;

  float u0[NP], u[NP], v[NP], ut[NP], vt[NP], au[NP], av[NP], ev[NP], hl[4];

  #pragma unroll
  for (int j = 0; j < NP; ++j) {
    int t = tb + j;
    float xv = (t >= 0 && t < T_DIM) ? xp[(size_t)t * D_DIM] : 0.f;
    // fast tanh: 2*tanh(x) = 2 - 4/(e^{2x}+1); clamp avoids inf/inf
    float xc = fminf(fmaxf(xv, -9.f), 9.f);
    float ex = __expf(2.f * xc);
    u0[j] = 2.f - 4.f * __builtin_amdgcn_rcpf(ex + 1.f);
  }

  // ---------------- sine-Gordon (2nd order, dt = 0.05) ----------------
  {
    const float dt = 0.05f, h = 0.025f, w6 = dt * (1.f / 6.f);
    #pragma unroll
    for (int j = 0; j < NP; ++j) { u[j] = u0[j]; v[j] = 0.f; }
    #pragma unroll 1
    for (int s = 0; s < 3; ++s) {
      XCHG(u);
      #pragma unroll
      for (int i = NP - 1; i >= 0; --i) {            // k1
        float k = sg_rhs(u[i], AT(u, i - 1), AT(u, i - 2), v[i]);
        au[i] = v[i]; av[i] = k;
        ut[i] = fmaf(h, v[i], u[i]);
        vt[i] = fmaf(h, k, v[i]);
      }
      XCHG(ut);
      #pragma unroll
      for (int i = NP - 1; i >= 0; --i) {            // k2
        float k = sg_rhs(ut[i], AT(ut, i - 1), AT(ut, i - 2), vt[i]);
        au[i] = fmaf(2.f, vt[i], au[i]); av[i] = fmaf(2.f, k, av[i]);
        float nu = fmaf(h, vt[i], u[i]);             // u + h*k2u (k2u = old vt)
        vt[i] = fmaf(h, k, v[i]);
        ut[i] = nu;
      }
      XCHG(ut);
      #pragma unroll
      for (int i = NP - 1; i >= 0; --i) {            // k3
        float k = sg_rhs(ut[i], AT(ut, i - 1), AT(ut, i - 2), vt[i]);
        au[i] = fmaf(2.f, vt[i], au[i]); av[i] = fmaf(2.f, k, av[i]);
        float nu = fmaf(dt, vt[i], u[i]);
        vt[i] = fmaf(dt, k, v[i]);
        ut[i] = nu;
      }
      XCHG(ut);
      #pragma unroll
      for (int i = NP - 1; i >= 0; --i) {            // k4 + combine
        float k = sg_rhs(ut[i], AT(ut, i - 1), AT(ut, i - 2), vt[i]);
        au[i] += vt[i]; av[i] += k;
        u[i] = fmaf(w6, au[i], u[i]);
        v[i] = fmaf(w6, av[i], v[i]);
      }
    }
    #pragma unroll
    for (int j = 0; j < NP; ++j) ev[j] = w0 * u[j];
  }

  // ---------------- KdV (1st order, dt = 0.025) ----------------
  {
    const float dt = 0.025f, h = 0.0125f, w6 = dt * (1.f / 6.f);
    #pragma unroll
    for (int j = 0; j < NP; ++j) u[j] = u0[j];
    #pragma unroll 1
    for (int s = 0; s < 3; ++s) {
      XCHG(u);
      #pragma unroll
      for (int i = NP - 1; i >= 0; --i) {            // k1
        float k = kdv_rhs(u[i], AT(u, i - 1), AT(u, i - 2), AT(u, i - 3));
        au[i] = k;
        ut[i] = fmaf(h, k, u[i]);
      }
      XCHG(ut);
      #pragma unroll
      for (int i = NP - 1; i >= 0; --i) {            // k2
        float k = kdv_rhs(ut[i], AT(ut, i - 1), AT(ut, i - 2), AT(ut, i - 3));
        au[i] = fmaf(2.f, k, au[i]);
        ut[i] = fmaf(h, k, u[i]);
      }
      XCHG(ut);
      #pragma unroll
      for (int i = NP - 1; i >= 0; --i) {            // k3
        float k = kdv_rhs(ut[i], AT(ut, i - 1), AT(ut, i - 2), AT(ut, i - 3));
        au[i] = fmaf(2.f, k, au[i]);
        ut[i] = fmaf(dt, k, u[i]);
      }
      XCHG(ut);
      #pragma unroll
      for (int i = NP - 1; i >= 0; --i) {            // k4 + combine
        float k = kdv_rhs(ut[i], AT(ut, i - 1), AT(ut, i - 2), AT(ut, i - 3));
        u[i] = fmaf(w6, au[i] + k, u[i]);
      }
    }
    #pragma unroll
    for (int j = 0; j < NP; ++j) ev[j] = fmaf(w1, u[j], ev[j]);
  }

  // ---------------- Heimburg-Jackson (2nd order, dt = 0.025) ----------------
  {
    const float dt = 0.025f, h = 0.0125f, w6 = dt * (1.f / 6.f);
    float g[NP], gB;
    // per-substep: XCHG(SRC); precompute g[] (old values); then descending
    // in-place update. g uses only SRC[i], SRC[i-1] -> safe before update.
#define HJ_GPRE(SRC) do {                                                  \
      gB = hj_g(hl[3], hl[2]);                                             \
      _Pragma("unroll")                                                    \
      for (int i_ = 0; i_ < NP; ++i_)                                      \
        g[i_] = hj_g(SRC[i_], AT(SRC, i_ - 1));                            \
    } while (0)
#define DG(i) ((i) ? (g[(i) - 1]) : gB)

    #pragma unroll
    for (int j = 0; j < NP; ++j) { u[j] = u0[j]; v[j] = 0.f; }
    #pragma unroll 1
    for (int s = 0; s < 3; ++s) {
      XCHG(u);
      HJ_GPRE(u);
      #pragma unroll
      for (int i = NP - 1; i >= 0; --i) {            // k1
        float k = hj_rhs2(u[i], AT(u, i - 1), AT(u, i - 2), AT(u, i - 3),
                          AT(u, i - 4), g[i] - DG(i), v[i]);
        au[i] = v[i]; av[i] = k;
        ut[i] = fmaf(h, v[i], u[i]);
        vt[i] = fmaf(h, k, v[i]);
      }
      XCHG(ut);
      HJ_GPRE(ut);
      #pragma unroll
      for (int i = NP - 1; i >= 0; --i) {            // k2
        float k = hj_rhs2(ut[i], AT(ut, i - 1), AT(ut, i - 2), AT(ut, i - 3),
                          AT(ut, i - 4), g[i] - DG(i), vt[i]);
        au[i] = fmaf(2.f, vt[i], au[i]); av[i] = fmaf(2.f, k, av[i]);
        float nu = fmaf(h, vt[i], u[i]);
        vt[i] = fmaf(h, k, v[i]);
        ut[i] = nu;
      }
      XCHG(ut);
      HJ_GPRE(ut);
      #pragma unroll
      for (int i = NP - 1; i >= 0; --i) {            // k3
        float k = hj_rhs2(ut[i], AT(ut, i - 1), AT(ut, i - 2), AT(ut, i - 3),
                          AT(ut, i - 4), g[i] - DG(i), vt[i]);
        au[i] = fmaf(2.f, vt[i], au[i]); av[i] = fmaf(2.f, k, av[i]);
        float nu = fmaf(dt, vt[i], u[i]);
        vt[i] = fmaf(dt, k, v[i]);
        ut[i] = nu;
      }
      XCHG(ut);
      HJ_GPRE(ut);
      #pragma unroll
      for (int i = NP - 1; i >= 0; --i) {            // k4 + combine
        float k = hj_rhs2(ut[i], AT(ut, i - 1), AT(ut, i - 2), AT(ut, i - 3),
                          AT(ut, i - 4), g[i] - DG(i), vt[i]);
        au[i] += vt[i]; av[i] += k;
        u[i] = fmaf(w6, au[i], u[i]);
        v[i] = fmaf(w6, av[i], v[i]);
      }
    }
#undef HJ_GPRE
#undef DG
    #pragma unroll
    for (int j = 0; j < NP; ++j) ev[j] = fmaf(w2, u[j], ev[j]);
  }

  // store interior chunks (tr >= HALO/NP) as bf16 A-matrix [b*T+t][d]
  if (tr >= HALO / NP) {
    #pragma unroll
    for (int j = 0; j < NP; ++j) {
      int t = tb + j;
      if (t < T_DIM)
        evout[((size_t)(b * T_DIM + t)) * D_DIM + d] = (__bf16)ev[j];
    }
  }
}

// ---------------------------------------------------------------------------
// W (fp32, [E][D]) -> bf16
// ---------------------------------------------------------------------------
__global__ __launch_bounds__(256)
void convert_w(const float* __restrict__ W, __bf16* __restrict__ Wb) {
  int i = blockIdx.x * 256 + threadIdx.x;   // over D*D/4
  float4 f = ((const float4*)W)[i];
  bf16x4 o = {(__bf16)f.x, (__bf16)f.y, (__bf16)f.z, (__bf16)f.w};
  ((bf16x4*)Wb)[i] = o;
}

// ---------------------------------------------------------------------------
// GEMM: out[m][n] = sum_k A[m][k] * Wb[n][k] + bias[n]
// M=16384, N=1024, K=1024.
//
// 256x256 block tile, BK=64, 512 threads / 8 waves (2Mx4N, each wave a
// 128x64 output tile, acc[8][4]), mfma_f32_16x16x32_bf16. Double-buffered
// LDS (128 KiB). R7: counted-vmcnt pipeline (T4) — per iteration:
//   STAGE(next)                       // 8 global_load_lds, stay in flight
//   s_waitcnt vmcnt(8); s_barrier     // only CUR's 8 loads waited on
//   ds_read + 64 MFMA (cur)
//   s_waitcnt lgkmcnt(0); s_barrier   // all waves done reading cur
// (R6's __syncthreads drained vmcnt(0) -> prefetch never pipelined.)
// Peeled final iteration waits vmcnt(0). XOR-granule LDS swizzle (granule
// kc of row r at slot kc^(r&7)), inverse-swizzled on the global source.
// Grid (64,4): same-A blocks 64 apart (64%8==0 -> same XCD L2).
// ---------------------------------------------------------------------------
#define GK   1024

__global__ __launch_bounds__(512, 1)
void gemm_kernel(const __bf16* __restrict__ A, const __bf16* __restrict__ Bw,
                 const float* __restrict__ bias, float* __restrict__ out) {
  __shared__ __align__(16) __bf16 As[2][256 * 64];   // 2 x 32 KB
  __shared__ __align__(16) __bf16 Bs[2][256 * 64];   // 2 x 32 KB

  const int tid  = threadIdx.x;
  const int lane = tid & 63;
  const int wid  = tid >> 6;           // 0..7
  const int m0   = blockIdx.x * 256;
  const int n0   = blockIdx.y * 256;
  const int wm   = (wid >> 2) * 128;   // 0 or 128
  const int wn   = (wid & 3) * 64;     // 0..192
  const int l15  = lane & 15;
  const int quad = lane >> 4;

  // staging: each global_load_lds covers 8 rows x 64 cols; lane i -> row
  // (i>>3) of the 8-row block, swizzled granule kc = (i&7) ^ row; LDS dest
  // is wave-uniform base + lane*16 (HW rule).
  const int sr  = lane >> 3;                 // 0..7 row within 8-row block
  const int skc = (lane & 7) ^ sr;           // inverse-swizzled global granule

  // wave w stages rows [w*32, w*32+32) of both tiles (4 instrs each)
  const __bf16* aBase = A  + (size_t)(m0 + wid * 32 + sr) * GK + skc * 8;
  const __bf16* bBase = Bw + (size_t)(n0 + wid * 32 + sr) * GK + skc * 8;

#define STAGE(buf, kt) do {                                                   \
    _Pragma("unroll")                                                         \
    for (int p = 0; p < 4; ++p)                                               \
      __builtin_amdgcn_global_load_lds(                                       \
          (const uint32_t*)(aBase + (size_t)(p * 8) * GK + (kt)),             \
          (uint32_t*)&As[buf][(wid * 32 + p * 8) * 64], 16, 0, 0);            \
    _Pragma("unroll")                                                         \
    for (int p = 0; p < 4; ++p)                                               \
      __builtin_amdgcn_global_load_lds(                                       \
          (const uint32_t*)(bBase + (size_t)(p * 8) * GK + (kt)),             \
          (uint32_t*)&Bs[buf][(wid * 32 + p * 8) * 64], 16, 0, 0);            \
  } while (0)

#define COMPUTE(buf) do {                                                     \
    const __bf16* as_ = As[buf];                                              \
    const __bf16* bs_ = Bs[buf];                                              \
    _Pragma("unroll")                                                         \
    for (int c = 0; c < 2; ++c) {           /* two K=32 chunks */             \
      bf16x8 af[8], bfr[4];                                                   \
      int kcg = c * 4 + quad;               /* global 16B granule in row */   \
      _Pragma("unroll")                                                       \
      for (int i = 0; i < 8; ++i) {                                           \
        int ra = wm + i * 16 + l15;                                           \
        af[i] = *(const bf16x8*)(&as_[ra * 64 + ((kcg ^ (ra & 7)) * 8)]);     \
      }                                                                       \
      _Pragma("unroll")                                                       \
      for (int j = 0; j < 4; ++j) {                                           \
        int rb = wn + j * 16 + l15;                                           \
        bfr[j] = *(const bf16x8*)(&bs_[rb * 64 + ((kcg ^ (rb & 7)) * 8)]);    \
      }                                                                       \
      _Pragma("unroll")                                                       \
      for (int i = 0; i < 8; ++i)                                             \
        _Pragma("unroll")                                                     \
        for (int j = 0; j < 4; ++j)                                           \
          acc[i][j] = __builtin_amdgcn_mfma_f32_16x16x32_bf16(                \
              af[i], bfr[j], acc[i][j], 0, 0, 0);                             \
    }                                                                         \
  } while (0)

  floatx4 acc[8][4] = {};

  STAGE(0, 0);
  int cur = 0;
  for (int kt = 64; kt < GK; kt += 64) {    // 15 pipelined iterations
    STAGE(cur ^ 1, kt);                     // 8 prefetch loads in flight
    asm volatile("s_waitcnt vmcnt(8)" ::: "memory");  // cur's 8 landed
    __builtin_amdgcn_sched_barrier(0);
    __builtin_amdgcn_s_barrier();           // all waves: cur ready
    __builtin_amdgcn_sched_barrier(0);
    COMPUTE(cur);
    asm volatile("s_waitcnt lgkmcnt(0)" ::: "memory"); // my ds_reads done
    __builtin_amdgcn_sched_barrier(0);
    __builtin_amdgcn_s_barrier();           // all waves done reading cur
    __builtin_amdgcn_sched_barrier(0);
    cur ^= 1;
  }
  // final tile: nothing left to prefetch -> full drain
  asm volatile("s_waitcnt vmcnt(0)" ::: "memory");
  __builtin_amdgcn_sched_barrier(0);
  __builtin_amdgcn_s_barrier();
  __builtin_amdgcn_sched_barrier(0);
  COMPUTE(cur);
#undef STAGE
#undef COMPUTE

  // epilogue: D[m=quad*4+r][n=l15] per 16x16 tile; add bias
  #pragma unroll
  for (int j = 0; j < 4; ++j) {
    int n = n0 + wn + j * 16 + l15;
    float bv = bias[n];
    #pragma unroll
    for (int i = 0; i < 8; ++i) {
      int mb = m0 + wm + i * 16 + quad * 4;
      #pragma unroll
      for (int r = 0; r < 4; ++r)
        out[(size_t)(mb + r) * 1024 + n] = acc[i][j][r] + bv;
    }
  }
}

// ---------------------------------------------------------------------------
extern "C" void kernel_launch(void* const* d_in, const int* in_sizes, int n_in,
                              void* d_out, int out_size, void* d_ws, size_t ws_size,
                              hipStream_t stream) {
  const float* x    = (const float*)d_in[0];
  const float* mix  = (const float*)d_in[1];
  const float* W    = (const float*)d_in[2];
  const float* bias = (const float*)d_in[3];
  float* out = (float*)d_out;

  __bf16* ev = (__bf16*)d_ws;                                     // 32 MiB
  __bf16* Wb = (__bf16*)((char*)d_ws + (size_t)32 * 1024 * 1024); // 2 MiB

  convert_w<<<dim3((D_DIM * D_DIM / 4) / 256), 256, 0, stream>>>(W, Wb);
  pde_kernel<<<dim3(NTT, D_DIM / 4, 4), 256, 0, stream>>>(x, mix, ev);
  gemm_kernel<<<dim3(16384 / 256, 1024 / 256), 512, 0, stream>>>(ev, Wb, bias, out);
}